// Round 1
// baseline (340.995 us; speedup 1.0000x reference)
//
#include <hip/hip_runtime.h>

// Problem constants
constexpr int BB = 8, NN = 4096, FF = 512, DD = 64, OO = 512;
constexpr int MROWS = BB * NN;          // 32768
constexpr int NCAT = 640;               // 64(q) + 64(k) + 512(support)

using short8  = __attribute__((ext_vector_type(8))) short;
using ushort8 = __attribute__((ext_vector_type(8))) unsigned short;
using ushort4v= __attribute__((ext_vector_type(4))) unsigned short;
using f32x4   = __attribute__((ext_vector_type(4))) float;

__device__ __forceinline__ unsigned short f2bf(float f) {
  unsigned int u = __builtin_bit_cast(unsigned int, f);
  return (unsigned short)((u + 0x7FFFu + ((u >> 16) & 1u)) >> 16);
}

__device__ __forceinline__ f32x4 mfma16(short8 a, short8 b, f32x4 c) {
  return __builtin_amdgcn_mfma_f32_16x16x32_bf16(a, b, c, 0, 0, 0);
}

// async global->LDS, 16B per lane; lds base must be wave-uniform (lane l lands at base + l*16)
__device__ __forceinline__ void gl_lds16(const void* g, void* s) {
  __builtin_amdgcn_global_load_lds(
      (const __attribute__((address_space(1))) unsigned int*)g,
      (__attribute__((address_space(3))) unsigned int*)s,
      16, 0, 0);
}

// ---------------- kernel 1: cast x (f32) -> bf16 ----------------
__global__ void cast_x(const float* __restrict__ x, unsigned short* __restrict__ xb) {
  size_t base = ((size_t)blockIdx.x * 256 + threadIdx.x) * 8;
  float4 a = *(const float4*)(x + base);
  float4 b = *(const float4*)(x + base + 4);
  ushort8 o;
  o[0]=f2bf(a.x); o[1]=f2bf(a.y); o[2]=f2bf(a.z); o[3]=f2bf(a.w);
  o[4]=f2bf(b.x); o[5]=f2bf(b.y); o[6]=f2bf(b.z); o[7]=f2bf(b.w);
  *(ushort8*)(xb + base) = o;
}

// ---------------- kernel 2: build Wcat^T [640][512] bf16 + bias[640] ----------------
__global__ void build_w(const float* __restrict__ w1, const float* __restrict__ w2,
                        const float* __restrict__ wgt,
                        const float* __restrict__ b1, const float* __restrict__ b2,
                        unsigned short* __restrict__ Wt, float* __restrict__ bias) {
  int idx = blockIdx.x * 256 + threadIdx.x;   // 640*512 threads
  int j = idx >> 9, kk = idx & 511;
  float v = (j < 64) ? w1[kk * 64 + j]
          : (j < 128) ? w2[kk * 64 + (j - 64)]
                      : wgt[(size_t)kk * 512 + (j - 128)];
  Wt[(size_t)j * 512 + kk] = f2bf(v);
  if (kk == 0) bias[j] = (j < 64) ? b1[j] : (j < 128) ? b2[j - 64] : 0.f;
}

// ---------------- kernel 3: fused projection GEMM ----------------
// Y = Xb[32768,512] @ Wcat[512,640]; cols 0..127 -> QK row-major [32768][128],
// cols 128..639 -> supportT [8*512][4096] (transposed store).
__global__ __launch_bounds__(256, 2) void proj_gemm(
    const unsigned short* __restrict__ X, const unsigned short* __restrict__ Wt,
    const float* __restrict__ bias,
    unsigned short* __restrict__ QK, unsigned short* __restrict__ SupT) {
  __shared__ __align__(16) unsigned short Abuf[128 * 64];
  __shared__ __align__(16) unsigned short Bbuf[128 * 64];
  const int t = threadIdx.x, lane = t & 63, w = t >> 6;
  const int nblk = blockIdx.x;           // 0..4
  const int m0 = blockIdx.y * 128, n0 = nblk * 128;
  const int wm = w & 1, wn = w >> 1;

  f32x4 acc[4][4] = {};
  for (int kt = 0; kt < 8; ++kt) {
    for (int i = 0; i < 4; ++i) {
      int c = i * 4 + w;
      int row = c * 8 + (lane >> 3);
      int k0 = (lane & 7) * 8;
      gl_lds16(X + (size_t)(m0 + row) * 512 + kt * 64 + k0, &Abuf[c * 512]);
      gl_lds16(Wt + (size_t)(n0 + row) * 512 + kt * 64 + k0, &Bbuf[c * 512]);
    }
    __syncthreads();
    short8 af[4][2], bfr[4][2];
    for (int mi = 0; mi < 4; ++mi)
      for (int kc = 0; kc < 2; ++kc) {
        int row = wm * 64 + mi * 16 + (lane & 15);
        int d = kc * 32 + (lane >> 4) * 8;
        af[mi][kc] = *(const short8*)&Abuf[row * 64 + d];
      }
    for (int ni = 0; ni < 4; ++ni)
      for (int kc = 0; kc < 2; ++kc) {
        int col = wn * 64 + ni * 16 + (lane & 15);
        int d = kc * 32 + (lane >> 4) * 8;
        bfr[ni][kc] = *(const short8*)&Bbuf[col * 64 + d];
      }
    for (int mi = 0; mi < 4; ++mi)
      for (int ni = 0; ni < 4; ++ni)
        for (int kc = 0; kc < 2; ++kc)
          acc[mi][ni] = mfma16(af[mi][kc], bfr[ni][kc], acc[mi][ni]);
    __syncthreads();
  }
  for (int mi = 0; mi < 4; ++mi)
    for (int ni = 0; ni < 4; ++ni) {
      int col_g = n0 + wn * 64 + ni * 16 + (lane & 15);
      int row0 = m0 + wm * 64 + mi * 16 + ((lane >> 4) * 4);
      float bv = bias[col_g];
      if (nblk == 0) {
        for (int j = 0; j < 4; ++j)
          QK[(size_t)(row0 + j) * 128 + col_g] = f2bf(acc[mi][ni][j] + bv);
      } else {
        int scol = col_g - 128;
        int b = row0 >> 12, rl = row0 & 4095;
        ushort4v pk;
        for (int j = 0; j < 4; ++j) pk[j] = f2bf(acc[mi][ni][j] + bv);
        *(ushort4v*)&SupT[(size_t)(b * 512 + scol) * 4096 + rl] = pk;
      }
    }
}

// ---------------- kernel 4: per-row softmax stats (max m, 1/sum(exp)) ----------------
// One block = 64 query rows; 4 waves x 16 rows. K tiles of 64 keys, XOR-source-swizzled LDS.
__global__ __launch_bounds__(256, 2) void stats_kernel(
    const unsigned short* __restrict__ QK, float* __restrict__ mrow, float* __restrict__ ilrow) {
  __shared__ __align__(16) unsigned short Kb[64 * 64];
  const int t = threadIdx.x, lane = t & 63, w = t >> 6;
  const int r0 = blockIdx.x * 64;
  const int keybase = (r0 >> 12) << 12;

  short8 aq[2];
  {
    int row = r0 + w * 16 + (lane & 15);
    for (int kc = 0; kc < 2; ++kc)
      aq[kc] = *(const short8*)&QK[(size_t)row * 128 + kc * 32 + (lane >> 4) * 8];
  }
  float m[4], l[4];
  for (int j = 0; j < 4; ++j) { m[j] = -1e30f; l[j] = 0.f; }

  for (int kt = 0; kt < 64; ++kt) {
    int key0 = kt * 64;
    for (int i = 0; i < 2; ++i) {
      int c = i * 4 + w;
      int key = c * 8 + (lane >> 3);
      int q = lane & 7;
      int d0 = (q ^ (key & 7)) * 8;
      gl_lds16(QK + (size_t)(keybase + key0 + key) * 128 + 64 + d0, &Kb[c * 512]);
    }
    __syncthreads();
    f32x4 s[4];
    for (int ni = 0; ni < 4; ++ni) {
      f32x4 sa = {0.f, 0.f, 0.f, 0.f};
      int key = ni * 16 + (lane & 15);
      for (int kc = 0; kc < 2; ++kc) {
        int dblk = kc * 4 + (lane >> 4);
        int blk = dblk ^ (key & 7);
        short8 bk = *(const short8*)&Kb[key * 64 + blk * 8];
        sa = mfma16(aq[kc], bk, sa);
      }
      s[ni] = sa;
    }
    for (int j = 0; j < 4; ++j) {
      float tm = -1e30f;
      for (int ni = 0; ni < 4; ++ni) tm = fmaxf(tm, s[ni][j]);
      tm *= 0.125f;
      for (int off = 1; off < 16; off <<= 1) tm = fmaxf(tm, __shfl_xor(tm, off));
      float nm = fmaxf(m[j], tm);
      float ts = 0.f;
      for (int ni = 0; ni < 4; ++ni) ts += __expf(s[ni][j] * 0.125f - nm);
      for (int off = 1; off < 16; off <<= 1) ts += __shfl_xor(ts, off);
      l[j] = l[j] * __expf(m[j] - nm) + ts;
      m[j] = nm;
    }
    __syncthreads();
  }
  if ((lane & 15) == 0) {
    int row = r0 + w * 16 + (lane >> 4) * 4;
    for (int j = 0; j < 4; ++j) { mrow[row + j] = m[j]; ilrow[row + j] = 1.f / l[j]; }
  }
}

// ---------------- kernel 5: attention (P = exp(s-m)/l, out = (P@V) * mask) ----------------
// Block: 64 rows x full O=512, 8 waves (2 row-halves x 4 col-groups), BK=32 keys/iter.
__global__ __launch_bounds__(512, 2) void attn_kernel(
    const unsigned short* __restrict__ QK, const unsigned short* __restrict__ SupT,
    const float* __restrict__ mrow, const float* __restrict__ ilrow,
    const float* __restrict__ mask, float* __restrict__ out) {
  __shared__ __align__(16) unsigned short Kb[32 * 64];   // xor-swizzled blocks
  __shared__ __align__(16) unsigned short Vt[512 * 32];  // [col][key], xor-swizzled blocks
  __shared__ __align__(16) unsigned short Pb[64 * 40];   // padded stride 40
  __shared__ float msh[64], ish[64];

  const int t = threadIdx.x, lane = t & 63, w = t >> 6;
  const int r0 = blockIdx.x * 64;
  const int b = r0 >> 12;
  const int keybase = b << 12;
  const int wm = w >> 2;                 // row half (0,1)
  const int wq = w & 3;
  const int fms = wq >> 1, ks = wq & 1;  // S-phase: which 16-row group / 16-key strip
  const int wo = w & 3;                  // PV: 128-col group

  if (t < 64) { msh[t] = mrow[r0 + t]; ish[t] = ilrow[r0 + t]; }
  __syncthreads();

  short8 aq[2];
  {
    int row = r0 + wm * 32 + fms * 16 + (lane & 15);
    for (int kc = 0; kc < 2; ++kc)
      aq[kc] = *(const short8*)&QK[(size_t)row * 128 + kc * 32 + (lane >> 4) * 8];
  }
  float msr[4], ilr[4];
  {
    int rl = wm * 32 + fms * 16 + (lane >> 4) * 4;
    for (int j = 0; j < 4; ++j) { msr[j] = msh[rl + j]; ilr[j] = ish[rl + j]; }
  }
  float maskr[2][4];
  for (int fm = 0; fm < 2; ++fm) {
    int rl = wm * 32 + fm * 16 + (lane >> 4) * 4;
    for (int j = 0; j < 4; ++j) maskr[fm][j] = mask[r0 + rl + j];
  }

  f32x4 acc[2][8] = {};

  for (int kt = 0; kt < 128; ++kt) {
    int key0 = kt * 32;
    if (w < 4) {  // stage K tile: 32 keys x 64 d
      int key = w * 8 + (lane >> 3);
      int q = lane & 7;
      int d0 = (q ^ (key & 7)) * 8;
      gl_lds16(QK + (size_t)(keybase + key0 + key) * 128 + 64 + d0, &Kb[w * 512]);
    }
    for (int i = 0; i < 4; ++i) {  // stage Vt tile: 512 cols x 32 keys
      int c = i * 8 + w;
      int col = c * 16 + (lane >> 2);
      int q = lane & 3;
      int k0 = (q ^ ((col >> 1) & 3)) * 8;
      gl_lds16(SupT + (size_t)(b * 512 + col) * 4096 + key0 + k0, &Vt[c * 512]);
    }
    __syncthreads();

    // S phase: this wave's 16 rows x 16 keys
    f32x4 sa = {0.f, 0.f, 0.f, 0.f};
    {
      int key = ks * 16 + (lane & 15);
      for (int kc = 0; kc < 2; ++kc) {
        int dblk = kc * 4 + (lane >> 4);
        int blk = dblk ^ (key & 7);
        short8 bk = *(const short8*)&Kb[key * 64 + blk * 8];
        sa = mfma16(aq[kc], bk, sa);
      }
      int rl0 = wm * 32 + fms * 16 + (lane >> 4) * 4;
      for (int j = 0; j < 4; ++j) {
        float p = __expf(sa[j] * 0.125f - msr[j]) * ilr[j];
        Pb[(rl0 + j) * 40 + key] = f2bf(p);
      }
    }
    __syncthreads();

    // PV phase
    short8 pa[2];
    for (int fm = 0; fm < 2; ++fm) {
      int row = wm * 32 + fm * 16 + (lane & 15);
      pa[fm] = *(const short8*)&Pb[row * 40 + (lane >> 4) * 8];
    }
    for (int ni = 0; ni < 8; ++ni) {
      int col = wo * 128 + ni * 16 + (lane & 15);
      int blk = (lane >> 4) ^ ((col >> 1) & 3);
      short8 vb = *(const short8*)&Vt[col * 32 + blk * 8];
      acc[0][ni] = mfma16(pa[0], vb, acc[0][ni]);
      acc[1][ni] = mfma16(pa[1], vb, acc[1][ni]);
    }
    __syncthreads();
  }

  for (int fm = 0; fm < 2; ++fm)
    for (int ni = 0; ni < 8; ++ni) {
      int col = wo * 128 + ni * 16 + (lane & 15);
      int row0 = r0 + wm * 32 + fm * 16 + (lane >> 4) * 4;
      for (int j = 0; j < 4; ++j)
        out[(size_t)(row0 + j) * 512 + col] = acc[fm][ni][j] * maskr[fm][j];
    }
}

extern "C" void kernel_launch(void* const* d_in, const int* in_sizes, int n_in,
                              void* d_out, int out_size, void* d_ws, size_t ws_size,
                              hipStream_t stream) {
  const float* x    = (const float*)d_in[0];
  const float* mask = (const float*)d_in[1];
  const float* w1   = (const float*)d_in[2];
  const float* b1   = (const float*)d_in[3];
  const float* w2   = (const float*)d_in[4];
  const float* b2   = (const float*)d_in[5];
  const float* wgt  = (const float*)d_in[6];
  float* out = (float*)d_out;

  char* ws = (char*)d_ws;
  unsigned short* Xb   = (unsigned short*)(ws);               // 33,554,432 B
  unsigned short* QK   = (unsigned short*)(ws + 33554432);    //  8,388,608 B
  unsigned short* SupT = (unsigned short*)(ws + 41943040);    // 33,554,432 B
  unsigned short* Wt   = (unsigned short*)(ws + 75497472);    //    655,360 B
  float* bias          = (float*)(ws + 76152832);             //      2,560 B
  float* mrow          = (float*)(ws + 76155392);             //    131,072 B
  float* ilrow         = (float*)(ws + 76286464);             //    131,072 B
  // total ~76.4 MB of d_ws

  build_w<<<dim3(1280), dim3(256), 0, stream>>>(w1, w2, wgt, b1, b2, Wt, bias);
  cast_x<<<dim3(8192), dim3(256), 0, stream>>>(x, Xb);
  proj_gemm<<<dim3(5, 256), dim3(256), 0, stream>>>(Xb, Wt, bias, QK, SupT);
  stats_kernel<<<dim3(512), dim3(256), 0, stream>>>(QK, mrow, ilrow);
  attn_kernel<<<dim3(512), dim3(512), 0, stream>>>(QK, SupT, mrow, ilrow, mask, out);
}